// Round 11
// baseline (318.067 us; speedup 1.0000x reference)
//
#include <hip/hip_runtime.h>
#include <hip/hip_bf16.h>
#include <hip/hip_fp8.h>

#define N_ROWS 8192
#define NZ 16384           // rows of Z = [An; Bn]
#define DIM 256
#define TAU_INV 2.0f
#define BT 128             // col tile width
#define AT 64              // row tile height (A strip)
#define NTILE 128          // NZ / BT  (col tiles)
#define NCHUNK 16
#define SEGT 4             // col tiles per segment
#define NSEG 4224          // sum over ri of ceil((128 - (ri>>1))/4)
#define PSTRIDE 1280       // floats/segment: 4*64 row-partials + 4*2*128 col-partials

typedef float f32x4 __attribute__((ext_vector_type(4)));
typedef long lx2 __attribute__((ext_vector_type(2)));   // 16B = 2 fp8 MFMA operands

// ---------------------------------------------------------------------------
// Kernel 1: one WAVE per row. L2-normalize, scale by 16, quantize to OCP fp8
// e4m3, write Z8 K-INTERLEAVED: each 64B chunk stores its eight 8B K-groups
// as [g0 g4 g1 g5 g2 g6 g3 g7] so one 16B granule = operand pair (g, g+4)
// for two consecutive MFMA K-steps. pos[i] = (1/256)*dot(quantized an, bn).
// ---------------------------------------------------------------------------
__global__ __launch_bounds__(256) void normalize_kernel(
    const float* __restrict__ z1, const float* __restrict__ z2,
    unsigned char* __restrict__ Z8, float* __restrict__ pos)
{
    const int tid = threadIdx.x;
    const int wave = tid >> 6;
    const int lane = tid & 63;
    const int row = blockIdx.x * 4 + wave;      // 0..8191

    const float4 a = ((const float4*)(z1 + (size_t)row * DIM))[lane];
    const float4 b = ((const float4*)(z2 + (size_t)row * DIM))[lane];

    auto wsum = [&](float v) -> float {
        #pragma unroll
        for (int m = 1; m < 64; m <<= 1) v += __shfl_xor(v, m, 64);
        return v;
    };

    const float na2 = wsum(a.x*a.x + a.y*a.y + a.z*a.z + a.w*a.w);
    const float nb2 = wsum(b.x*b.x + b.y*b.y + b.z*b.z + b.w*b.w);
    const float sa = 16.0f / sqrtf(na2);   // norms ~16; eps never binds
    const float sb = 16.0f / sqrtf(nb2);

    const float av[4] = {a.x*sa, a.y*sa, a.z*sa, a.w*sa};
    const float bv[4] = {b.x*sb, b.y*sb, b.z*sb, b.w*sb};
    unsigned char pa[4], pb[4];
    float qd = 0.0f;
    #pragma unroll
    for (int k = 0; k < 4; ++k) {
        __hip_fp8_e4m3 qa(av[k]);
        __hip_fp8_e4m3 qb(bv[k]);
        pa[k] = qa.__x; pb[k] = qb.__x;
        qd += float(qa) * float(qb);
    }
    const int g  = (lane >> 1) & 7;
    const int pp = ((g & 3) << 1) | (g >> 2);          // interleaved 8B slot
    const int off = (lane >> 4) * 64 + pp * 8 + (lane & 1) * 4;
    *(uchar4*)(Z8 + (size_t)row * DIM + off) = *(uchar4*)pa;
    *(uchar4*)(Z8 + (size_t)(N_ROWS + row) * DIM + off) = *(uchar4*)pb;

    qd = wsum(qd);
    if (lane == 0) pos[row] = qd * 0.00390625f;   // /256 -> quantized sim
}

// ---------------------------------------------------------------------------
// Kernel 2 (R11 = R10 with 512-thread blocks): symmetric fp8 gram, 64x128
// tiles, strip-segmented SEGT=4, 2-slot __syncthreads prefetch ring, A in
// registers, raw v_exp_f32 (R10 win). R2-R10 law: gram time tracks resident
// waves; R10 measured VGPR_Count=64 == the 8-waves/SIMD boundary. So: same
// tile, EIGHT waves/block (2 row-groups x 4 col-groups; 32x32 output/wave).
// Per-wave state halves (acc 16, A 16, B 4 live, ~56 total) -> fits the
// 64-VGPR cap of __launch_bounds__(512,8); LDS still 32KB -> 4 blocks/CU
// x 8 waves = 32 waves/CU (100% theoretical, 2x R10). Staging spread over
// 8 waves (2 gload_lds each); A duplicated x4 across col-waves (L2-trivial).
// B ring + swizzle verbatim (0 bank conflicts measured). Row partials in
// regs across the segment (now 4 wc entries/row -> PSTRIDE 1280).
// Spill tripwire (R8): FETCH must stay ~16MB; >100MB means the 64-cap spilled.
// ---------------------------------------------------------------------------
template <bool TWO_STAGE>
__global__ __launch_bounds__(512, 8) void gram_kernel(
    const unsigned char* __restrict__ Z,
    float* __restrict__ part, float* __restrict__ S)
{
    // XCD band remap over segments (4224 = 8 * 528), then segment decode.
    const int sid = (blockIdx.x & 7) * (NSEG / 8) + (blockIdx.x >> 3);
    // group g: strips ri = 8g..8g+7 each have v = 32-g segments;
    // cum(g) = 260g - 4g^2 segments before group g.
    int g = (int)((260.0f - sqrtf(67600.0f - 16.0f * (float)sid)) * 0.125f);
    g = g < 0 ? 0 : (g > 31 ? 31 : g);
    while (260 * g - 4 * g * g > sid) --g;
    while (g < 31 && 260 * (g + 1) - 4 * (g + 1) * (g + 1) <= sid) ++g;
    const int local = sid - (260 * g - 4 * g * g);
    const int v  = 32 - g;                 // segments per strip in this group
    const int r8i = local / v;
    const int s4 = local - r8i * v;
    const int ri = 8 * g + r8i;            // row strip 0..255
    const int tj0 = (ri >> 1) + SEGT * s4; // first col tile
    const int nt = (NTILE - tj0 < SEGT) ? (NTILE - tj0) : SEGT;

    __shared__ unsigned char Ls[32768];   // B ring slots 0/1 (16KB each)

    const int tid  = threadIdx.x;
    const int wv   = tid >> 6;             // 0..7
    const int lane = tid & 63;
    const int wr = wv >> 2, wc = wv & 3;   // wave grid 2x4 over 64x128
    const int lm = lane & 15, lq = lane >> 4;

    // ---- A fragments: global -> regs once per segment (R5/R7-proven layout)
    lx2 aR[2][2][2];                       // [kh][set][fr]
    {
        const unsigned char* pa =
            Z + (size_t)(ri * AT + wr * 32 + lm) * DIM + lq * 16;
        #pragma unroll
        for (int fr = 0; fr < 2; ++fr)
            #pragma unroll
            for (int kh = 0; kh < 2; ++kh)
                #pragma unroll
                for (int s = 0; s < 2; ++s)
                    aR[kh][s][fr] =
                        *(const lx2*)(pa + fr * 4096 + kh * 128 + s * 64);
    }

    // ---- staging lane geometry (width-16: 1KB instr = 8 rows x 8 granules)
    // wave wv stages B rows wv*16..+15 (2 chunks); swizzle verbatim R10.
    const int r8 = lane >> 3;                   // row within 8-row group
    const int pg = lane & 7;                    // LDS granule slot
    const int G0 = pg ^ (r8 >> 1);              // global granule, even chunks
    const int dlt = 64 - ((G0 & 4) << 5);       // odd chunks: granule G0^4
    const unsigned char* pB0 =
        Z + (size_t)(tj0 * BT + wv * 16 + r8) * DIM + (G0 << 4);

    auto stageB = [&](const unsigned char* pb, int kh, int sl) {
        #pragma unroll
        for (int c = 0; c < 2; ++c) {           // rows wv*16 + c*8 + r8
            const unsigned char* gb = ((c & 1) ? pb + dlt : pb) + c * 2048 + kh * 128;
            __builtin_amdgcn_global_load_lds(
                (const __attribute__((address_space(1))) void*)gb,
                (__attribute__((address_space(3))) void*)
                    (Ls + sl * 16384 + (wv * 2 + c) * 1024), 16, 0, 0);
        }
    };

    stageB(pB0, 0, 0);   // prologue: B(tile0, kh0) -> slot0

    // ---- B frag-read bases (invariant across the segment; R4/R10 swizzle)
    const int s0 = (lq ^ (lm >> 1)) << 4;       // slot of granule lq
    const int s1 = s0 ^ 64;                     // slot of granule lq^4
    const unsigned char* LB = Ls + (wc * 32 + lm) * 128;   // + slot*16K

    const float SC = 2.8853900817779268f / 256.0f;   // exp(2*sim), dot=256*sim

    f32x4 rowacc[2] = {};   // per-lane row partial, accumulated over segment

    for (int t = 0; t < nt; ++t) {
        f32x4 acc[2][2] = {};                   // [fr][fc]
        #pragma unroll
        for (int kh = 0; kh < 2; ++kh) {
            __syncthreads();    // drains stage(h) [one compute phase of cover]
            if (kh == 0)            stageB(pB0 + (size_t)t * 32768, 1, 1);
            else if (t + 1 < nt)    stageB(pB0 + (size_t)(t + 1) * 32768, 0, 0);

            const unsigned char* lb = LB + (kh << 14);   // slot == kh
            lx2 bP[2];
            __builtin_amdgcn_s_setprio(1);
            #pragma unroll
            for (int f = 0; f < 2; ++f) bP[f] = *(const lx2*)(lb + s0 + f * 2048);
            #pragma unroll
            for (int fr = 0; fr < 2; ++fr)
                #pragma unroll
                for (int fc = 0; fc < 2; ++fc) {
                    acc[fr][fc] = __builtin_amdgcn_mfma_f32_16x16x32_fp8_fp8(
                        aR[kh][0][fr].x, bP[fc].x, acc[fr][fc], 0, 0, 0);
                    acc[fr][fc] = __builtin_amdgcn_mfma_f32_16x16x32_fp8_fp8(
                        aR[kh][0][fr].y, bP[fc].y, acc[fr][fc], 0, 0, 0);
                }
            #pragma unroll
            for (int f = 0; f < 2; ++f) bP[f] = *(const lx2*)(lb + s1 + f * 2048);
            #pragma unroll
            for (int fr = 0; fr < 2; ++fr)
                #pragma unroll
                for (int fc = 0; fc < 2; ++fc) {
                    acc[fr][fc] = __builtin_amdgcn_mfma_f32_16x16x32_fp8_fp8(
                        aR[kh][1][fr].x, bP[fc].x, acc[fr][fc], 0, 0, 0);
                    acc[fr][fc] = __builtin_amdgcn_mfma_f32_16x16x32_fp8_fp8(
                        aR[kh][1][fr].y, bP[fc].y, acc[fr][fc], 0, 0, 0);
                }
            __builtin_amdgcn_s_setprio(0);
        }

        // ---- per-tile epilogue (LDS-free; overlaps in-flight stage)
        // raw v_exp_f32: args bounded to +-2.89, fixup-free (R10-proven)
        #pragma unroll
        for (int fr = 0; fr < 2; ++fr)
            #pragma unroll
            for (int fc = 0; fc < 2; ++fc)
                #pragma unroll
                for (int r = 0; r < 4; ++r)
                    acc[fr][fc][r] = __builtin_amdgcn_exp2f(acc[fr][fc][r] * SC);

        const int tj = tj0 + t;
        if (tj == (ri >> 1)) {   // only tile of the segment crossing diagonal
            const int add = (ri & 1) << 6;    // odd strip: rows sit 64 below
            #pragma unroll
            for (int fr = 0; fr < 2; ++fr) {
                const int ciloc = wr * 32 + fr * 16 + lq * 4;
                #pragma unroll
                for (int fc = 0; fc < 2; ++fc) {
                    const int cj = wc * 32 + fc * 16 + lm;
                    #pragma unroll
                    for (int r = 0; r < 4; ++r)
                        if (cj <= ciloc + r + add) acc[fr][fc][r] = 0.0f;
                }
            }
        }

        // row partials: accumulate in registers across the segment
        #pragma unroll
        for (int fr = 0; fr < 2; ++fr)
            #pragma unroll
            for (int r = 0; r < 4; ++r)
                rowacc[fr][r] += acc[fr][0][r] + acc[fr][1][r];

        // col partials per tile (B changes each tile); stores drained by sync
        float* dstc = TWO_STAGE ? (part + (size_t)sid * PSTRIDE + 256 + t * 256)
                                : nullptr;
        #pragma unroll
        for (int fc = 0; fc < 2; ++fc) {
            float s = 0.0f;
            #pragma unroll
            for (int fr = 0; fr < 2; ++fr)
                #pragma unroll
                for (int r = 0; r < 4; ++r) s += acc[fr][fc][r];
            s += __shfl_xor(s, 16, 64);
            s += __shfl_xor(s, 32, 64);
            if (lq == 0) {      // 16 lanes x 4B consecutive = full 64B line
                const int cc = wc * 32 + fc * 16 + lm;
                if (TWO_STAGE) dstc[wr * 128 + cc] = s;
                else atomicAdd(&S[tj * BT + cc], s);
            }
        }
    }

    // ---- segment epilogue: lane-reduce + store row partials ONCE
    // (4 wc-partials per row; summed in reduce_kernel)
    float* dstr = TWO_STAGE ? (part + (size_t)sid * PSTRIDE) : nullptr;
    #pragma unroll
    for (int fr = 0; fr < 2; ++fr) {
        f32x4 rs;
        #pragma unroll
        for (int r = 0; r < 4; ++r) {
            float s = rowacc[fr][r];
            s += __shfl_xor(s, 1, 64);
            s += __shfl_xor(s, 2, 64);
            s += __shfl_xor(s, 4, 64);
            s += __shfl_xor(s, 8, 64);
            rs[r] = s;
        }
        if (lm == 0) {          // 4 lanes x 16B consecutive = full 64B line
            const int rr = wr * 32 + fr * 16 + lq * 4;
            if (TWO_STAGE) *(f32x4*)(dstr + wc * 64 + rr) = rs;
            else {
                #pragma unroll
                for (int r = 0; r < 4; ++r)
                    atomicAdd(&S[ri * AT + rr + r], rs[r]);
            }
        }
    }
}

// ---------------------------------------------------------------------------
// Kernel 3: parallel partial gather. grid (NZ/256, NCHUNK).
// Row r: row-side = 4 wc-partials per segment of strip ri=r>>6;
// col-side = 2 entries (wr) per strip rip = 0..2*tj+1 hitting tile tj=r>>7.
// All reads coalesced. Zeroes out[0]. (PSTRIDE 1280: rows at 0, cols at 256.)
// ---------------------------------------------------------------------------
__global__ __launch_bounds__(256) void reduce_kernel(
    const float* __restrict__ part, float* __restrict__ S2,
    float* __restrict__ out)
{
    const int chunk = blockIdx.y;
    const int tid = threadIdx.x;
    const int r = blockIdx.x * 256 + tid;       // Z row
    const int ri = r >> 6, rr = r & 63;
    const int gg = ri >> 3;
    const int nseg = 32 - gg;
    const int sid0 = 260 * gg - 4 * gg * gg + (ri & 7) * nseg;
    const int tj = r >> 7, cc = r & 127;
    const int nr = 2 * tj + 2;                  // strips covering col tile tj
    const int T = 4 * nseg + 2 * nr;

    if (chunk == 0 && r == 0) out[0] = 0.0f;

    float s = 0.0f;
    for (int m = chunk; m < T; m += NCHUNK) {
        size_t addr;
        if (m < 4 * nseg) {
            addr = (size_t)(sid0 + (m >> 2)) * PSTRIDE + (m & 3) * 64 + rr;
        } else {
            const int m2 = m - 4 * nseg;
            const int rip = m2 >> 1;            // source strip
            const int dtj = tj - (rip >> 1);
            const int gp = rip >> 3;
            const int sidc = 260 * gp - 4 * gp * gp + (rip & 7) * (32 - gp)
                           + (dtj >> 2);
            addr = (size_t)sidc * PSTRIDE + 256 + (dtj & 3) * 256
                 + (m2 & 1) * 128 + cc;
        }
        s += part[addr];
    }
    S2[(size_t)chunk * NZ + r] = s;
}

// ---------------------------------------------------------------------------
// Kernel 4: loss + mean (two-stage path).
// ---------------------------------------------------------------------------
__global__ __launch_bounds__(256) void loss2_kernel(
    const float* __restrict__ S2, const float* __restrict__ pos,
    float* __restrict__ out)
{
    const int i = blockIdx.x * 256 + threadIdx.x;
    float den1 = 0.0f, den2 = 0.0f;
    #pragma unroll
    for (int c = 0; c < NCHUNK; ++c) {
        den1 += S2[(size_t)c * NZ + i];
        den2 += S2[(size_t)c * NZ + N_ROWS + i];
    }
    float v = 0.5f * (logf(den1) + logf(den2)) - TAU_INV * pos[i];

    __shared__ float red[4];
    #pragma unroll
    for (int m = 1; m < 64; m <<= 1) v += __shfl_xor(v, m, 64);
    if ((threadIdx.x & 63) == 0) red[threadIdx.x >> 6] = v;
    __syncthreads();
    if (threadIdx.x == 0)
        atomicAdd(out, (red[0] + red[1] + red[2] + red[3]) * (1.0f / N_ROWS));
}

// Fallback loss (atomic path, only if ws too small — never expected).
__global__ __launch_bounds__(256) void loss_kernel(
    const float* __restrict__ S, const float* __restrict__ pos,
    float* __restrict__ out)
{
    const int i = blockIdx.x * 256 + threadIdx.x;
    float v = 0.5f * (logf(S[i]) + logf(S[N_ROWS + i])) - TAU_INV * pos[i];

    __shared__ float red[4];
    #pragma unroll
    for (int m = 1; m < 64; m <<= 1) v += __shfl_xor(v, m, 64);
    if ((threadIdx.x & 63) == 0) red[threadIdx.x >> 6] = v;
    __syncthreads();
    if (threadIdx.x == 0)
        atomicAdd(out, (red[0] + red[1] + red[2] + red[3]) * (1.0f / N_ROWS));
}

// ---------------------------------------------------------------------------
extern "C" void kernel_launch(void* const* d_in, const int* in_sizes, int n_in,
                              void* d_out, int out_size, void* d_ws, size_t ws_size,
                              hipStream_t stream)
{
    const float* z1 = (const float*)d_in[0];
    const float* z2 = (const float*)d_in[1];
    float* out = (float*)d_out;

    char* ws = (char*)d_ws;
    unsigned char* Z8 = (unsigned char*)ws;              // 16384*256 = 4 MB
    float* pos  = (float*)(ws + 4194304);                // 32 KB
    float* S2   = (float*)(ws + 4227072);                // 16*16384*4 = 1 MB
    float* part = (float*)(ws + 5275648);                // 4224*1280*4 = 21.6 MB
    const size_t need = 5275648 + (size_t)NSEG * PSTRIDE * 4;

    normalize_kernel<<<N_ROWS / 4, 256, 0, stream>>>(z1, z2, Z8, pos);

    if (ws_size >= need) {
        gram_kernel<true><<<NSEG, 512, 0, stream>>>(Z8, part, nullptr);
        dim3 rg(NZ / 256, NCHUNK);
        reduce_kernel<<<rg, 256, 0, stream>>>(part, S2, out);   // zeroes out
        loss2_kernel<<<N_ROWS / 256, 256, 0, stream>>>(S2, pos, out);
    } else {
        hipMemsetAsync(S2, 0, NZ * sizeof(float), stream);
        hipMemsetAsync(out, 0, sizeof(float), stream);
        gram_kernel<false><<<NSEG, 512, 0, stream>>>(Z8, nullptr, S2);
        loss_kernel<<<N_ROWS / 256, 256, 0, stream>>>(S2, pos, out);
    }
}

// Round 12
// 163.923 us; speedup vs baseline: 1.9403x; 1.9403x over previous
//
#include <hip/hip_runtime.h>
#include <hip/hip_bf16.h>
#include <hip/hip_fp8.h>

#define N_ROWS 8192
#define NZ 16384           // rows of Z = [An; Bn]
#define DIM 256
#define TAU_INV 2.0f
#define BT 128             // col tile width
#define AT 64              // row tile height (A strip)
#define NTILE 128          // NZ / BT  (col tiles)
#define SEGT 4             // col tiles per segment
#define NSEG 4224          // sum over ri of ceil((128 - (ri>>1))/4)
#define PSTRIDE 1152       // floats/segment: 2*64 row-partials + 4*2*128 col-partials

typedef float f32x4 __attribute__((ext_vector_type(4)));
typedef long lx2 __attribute__((ext_vector_type(2)));   // 16B = 2 fp8 MFMA operands

// ---------------------------------------------------------------------------
// Kernel 1: one WAVE per row. L2-normalize, scale by 16, quantize to OCP fp8
// e4m3, write Z8 K-INTERLEAVED: each 64B chunk stores its eight 8B K-groups
// as [g0 g4 g1 g5 g2 g6 g3 g7] so one 16B granule = operand pair (g, g+4)
// for two consecutive MFMA K-steps. pos[i] = (1/256)*dot(quantized an, bn).
// Also zeroes out[0] (stream-ordered before the fused reduce+loss).
// ---------------------------------------------------------------------------
__global__ __launch_bounds__(256) void normalize_kernel(
    const float* __restrict__ z1, const float* __restrict__ z2,
    unsigned char* __restrict__ Z8, float* __restrict__ pos,
    float* __restrict__ out)
{
    const int tid = threadIdx.x;
    const int wave = tid >> 6;
    const int lane = tid & 63;
    const int row = blockIdx.x * 4 + wave;      // 0..8191

    if (blockIdx.x == 0 && tid == 0) out[0] = 0.0f;

    const float4 a = ((const float4*)(z1 + (size_t)row * DIM))[lane];
    const float4 b = ((const float4*)(z2 + (size_t)row * DIM))[lane];

    auto wsum = [&](float v) -> float {
        #pragma unroll
        for (int m = 1; m < 64; m <<= 1) v += __shfl_xor(v, m, 64);
        return v;
    };

    const float na2 = wsum(a.x*a.x + a.y*a.y + a.z*a.z + a.w*a.w);
    const float nb2 = wsum(b.x*b.x + b.y*b.y + b.z*b.z + b.w*b.w);
    const float sa = 16.0f / sqrtf(na2);   // norms ~16; eps never binds
    const float sb = 16.0f / sqrtf(nb2);

    const float av[4] = {a.x*sa, a.y*sa, a.z*sa, a.w*sa};
    const float bv[4] = {b.x*sb, b.y*sb, b.z*sb, b.w*sb};
    unsigned char pa[4], pb[4];
    float qd = 0.0f;
    #pragma unroll
    for (int k = 0; k < 4; ++k) {
        __hip_fp8_e4m3 qa(av[k]);
        __hip_fp8_e4m3 qb(bv[k]);
        pa[k] = qa.__x; pb[k] = qb.__x;
        qd += float(qa) * float(qb);
    }
    const int g  = (lane >> 1) & 7;
    const int pp = ((g & 3) << 1) | (g >> 2);          // interleaved 8B slot
    const int off = (lane >> 4) * 64 + pp * 8 + (lane & 1) * 4;
    *(uchar4*)(Z8 + (size_t)row * DIM + off) = *(uchar4*)pa;
    *(uchar4*)(Z8 + (size_t)(N_ROWS + row) * DIM + off) = *(uchar4*)pb;

    qd = wsum(qd);
    if (lane == 0) pos[row] = qd * 0.00390625f;   // /256 -> quantized sim
}

// ---------------------------------------------------------------------------
// Kernel 2 (VERBATIM R10 — measured best: gram 73.5us, VGPR 64, 0 conflicts):
// symmetric fp8 gram, 64x128 tiles, strip-segmented SEGT=4, 2-slot
// __syncthreads prefetch ring, A in registers, raw v_exp_f32.
// R11 lesson (m68/m69 quanta): HW wave slots step at VGPR<=64 (8/SIMD) and
// <=128 (4/SIMD) with NO intermediate; this kernel's ~70-reg wave cannot fit
// the 64-quantum -> 16 waves/CU is the occupancy ceiling. Schedule
// restructuring proven null (R6/R7). This structure is final.
// ---------------------------------------------------------------------------
template <bool TWO_STAGE>
__global__ __launch_bounds__(256, 4) void gram_kernel(
    const unsigned char* __restrict__ Z,
    float* __restrict__ part, float* __restrict__ S)
{
    // XCD band remap over segments (4224 = 8 * 528), then segment decode.
    const int sid = (blockIdx.x & 7) * (NSEG / 8) + (blockIdx.x >> 3);
    // group g: strips ri = 8g..8g+7 each have v = 32-g segments;
    // cum(g) = 260g - 4g^2 segments before group g.
    int g = (int)((260.0f - sqrtf(67600.0f - 16.0f * (float)sid)) * 0.125f);
    g = g < 0 ? 0 : (g > 31 ? 31 : g);
    while (260 * g - 4 * g * g > sid) --g;
    while (g < 31 && 260 * (g + 1) - 4 * (g + 1) * (g + 1) <= sid) ++g;
    const int local = sid - (260 * g - 4 * g * g);
    const int v  = 32 - g;                 // segments per strip in this group
    const int r8i = local / v;
    const int s4 = local - r8i * v;
    const int ri = 8 * g + r8i;            // row strip 0..255
    const int tj0 = (ri >> 1) + SEGT * s4; // first col tile
    const int nt = (NTILE - tj0 < SEGT) ? (NTILE - tj0) : SEGT;

    __shared__ unsigned char Ls[32768];   // B ring slots 0/1 (16KB each)

    const int tid  = threadIdx.x;
    const int wave = tid >> 6;
    const int lane = tid & 63;
    const int wr = wave >> 1, wc = wave & 1;   // wave grid 2x2 over 64x128
    const int lm = lane & 15, lq = lane >> 4;

    // ---- A fragments: global -> regs once per segment (R5/R7-proven layout)
    lx2 aR[2][2][2];                       // [kh][set][fr]
    {
        const unsigned char* pa =
            Z + (size_t)(ri * AT + wr * 32 + lm) * DIM + lq * 16;
        #pragma unroll
        for (int fr = 0; fr < 2; ++fr)
            #pragma unroll
            for (int kh = 0; kh < 2; ++kh)
                #pragma unroll
                for (int s = 0; s < 2; ++s)
                    aR[kh][s][fr] =
                        *(const lx2*)(pa + fr * 4096 + kh * 128 + s * 64);
    }

    // ---- staging lane geometry (width-16: 1KB instr = 8 rows x 8 granules)
    const int r8 = lane >> 3;                   // row within 8-row group
    const int pg = lane & 7;                    // LDS granule slot
    const int G0 = pg ^ (r8 >> 1);              // global granule, even instrs
    const int dlt = 64 - ((G0 & 4) << 5);       // odd instrs: granule G0^4
    const unsigned char* pB0 =
        Z + (size_t)(tj0 * BT + wave * 32 + r8) * DIM + (G0 << 4);

    auto stageB = [&](const unsigned char* pb, int kh, int sl) {
        #pragma unroll
        for (int c = 0; c < 4; ++c) {           // rows wave*32 + c*8 + r8
            const unsigned char* gb = ((c & 1) ? pb + dlt : pb) + c * 2048 + kh * 128;
            __builtin_amdgcn_global_load_lds(
                (const __attribute__((address_space(1))) void*)gb,
                (__attribute__((address_space(3))) void*)
                    (Ls + sl * 16384 + (wave * 4 + c) * 1024), 16, 0, 0);
        }
    };

    stageB(pB0, 0, 0);   // prologue: B(tile0, kh0) -> slot0

    // ---- B frag-read bases (invariant across the segment; R4 swizzle)
    const int s0 = (lq ^ (lm >> 1)) << 4;       // slot of granule lq
    const int s1 = s0 ^ 64;                     // slot of granule lq^4
    const unsigned char* LB = Ls + (wc * 64 + lm) * 128;   // + slot*16K

    const float SC = 2.8853900817779268f / 256.0f;   // exp(2*sim), dot=256*sim

    f32x4 rowacc[2] = {};   // per-lane row partial, accumulated over segment

    for (int t = 0; t < nt; ++t) {
        f32x4 acc[2][4] = {};
        #pragma unroll
        for (int kh = 0; kh < 2; ++kh) {
            __syncthreads();    // drains stage(h) [one compute phase of cover]
            if (kh == 0)            stageB(pB0 + (size_t)t * 32768, 1, 1);
            else if (t + 1 < nt)    stageB(pB0 + (size_t)(t + 1) * 32768, 0, 0);

            const unsigned char* lb = LB + (kh << 14);   // slot == kh
            lx2 bP[4];
            __builtin_amdgcn_s_setprio(1);
            #pragma unroll
            for (int f = 0; f < 4; ++f) bP[f] = *(const lx2*)(lb + s0 + f * 2048);
            #pragma unroll
            for (int fr = 0; fr < 2; ++fr)
                #pragma unroll
                for (int fc = 0; fc < 4; ++fc) {
                    acc[fr][fc] = __builtin_amdgcn_mfma_f32_16x16x32_fp8_fp8(
                        aR[kh][0][fr].x, bP[fc].x, acc[fr][fc], 0, 0, 0);
                    acc[fr][fc] = __builtin_amdgcn_mfma_f32_16x16x32_fp8_fp8(
                        aR[kh][0][fr].y, bP[fc].y, acc[fr][fc], 0, 0, 0);
                }
            #pragma unroll
            for (int f = 0; f < 4; ++f) bP[f] = *(const lx2*)(lb + s1 + f * 2048);
            #pragma unroll
            for (int fr = 0; fr < 2; ++fr)
                #pragma unroll
                for (int fc = 0; fc < 4; ++fc) {
                    acc[fr][fc] = __builtin_amdgcn_mfma_f32_16x16x32_fp8_fp8(
                        aR[kh][1][fr].x, bP[fc].x, acc[fr][fc], 0, 0, 0);
                    acc[fr][fc] = __builtin_amdgcn_mfma_f32_16x16x32_fp8_fp8(
                        aR[kh][1][fr].y, bP[fc].y, acc[fr][fc], 0, 0, 0);
                }
            __builtin_amdgcn_s_setprio(0);
        }

        // ---- per-tile epilogue (LDS-free; overlaps in-flight stage)
        // raw v_exp_f32: args bounded to +-2.89, fixup-free (R10-proven)
        #pragma unroll
        for (int fr = 0; fr < 2; ++fr)
            #pragma unroll
            for (int fc = 0; fc < 4; ++fc)
                #pragma unroll
                for (int r = 0; r < 4; ++r)
                    acc[fr][fc][r] = __builtin_amdgcn_exp2f(acc[fr][fc][r] * SC);

        const int tj = tj0 + t;
        if (tj == (ri >> 1)) {   // only tile of the segment crossing diagonal
            const int add = (ri & 1) << 6;    // odd strip: rows sit 64 below
            #pragma unroll
            for (int fr = 0; fr < 2; ++fr) {
                const int ciloc = wr * 32 + fr * 16 + lq * 4;
                #pragma unroll
                for (int fc = 0; fc < 4; ++fc) {
                    const int cj = wc * 64 + fc * 16 + lm;
                    #pragma unroll
                    for (int r = 0; r < 4; ++r)
                        if (cj <= ciloc + r + add) acc[fr][fc][r] = 0.0f;
                }
            }
        }

        // row partials: accumulate in registers across the segment
        #pragma unroll
        for (int fr = 0; fr < 2; ++fr)
            #pragma unroll
            for (int r = 0; r < 4; ++r)
                rowacc[fr][r] += acc[fr][0][r] + acc[fr][1][r]
                               + acc[fr][2][r] + acc[fr][3][r];

        // col partials per tile (B changes each tile); stores drained by sync
        float* dstc = TWO_STAGE ? (part + (size_t)sid * PSTRIDE + 128 + t * 256)
                                : nullptr;
        #pragma unroll
        for (int fc = 0; fc < 4; ++fc) {
            float s = 0.0f;
            #pragma unroll
            for (int fr = 0; fr < 2; ++fr)
                #pragma unroll
                for (int r = 0; r < 4; ++r) s += acc[fr][fc][r];
            s += __shfl_xor(s, 16, 64);
            s += __shfl_xor(s, 32, 64);
            if (lq == 0) {      // 16 lanes x 4B consecutive = full 64B line
                const int cc = wc * 64 + fc * 16 + lm;
                if (TWO_STAGE) dstc[wr * 128 + cc] = s;
                else atomicAdd(&S[tj * BT + cc], s);
            }
        }
    }

    // ---- segment epilogue: lane-reduce + store row partials ONCE
    float* dstr = TWO_STAGE ? (part + (size_t)sid * PSTRIDE) : nullptr;
    #pragma unroll
    for (int fr = 0; fr < 2; ++fr) {
        f32x4 rs;
        #pragma unroll
        for (int r = 0; r < 4; ++r) {
            float s = rowacc[fr][r];
            s += __shfl_xor(s, 1, 64);
            s += __shfl_xor(s, 2, 64);
            s += __shfl_xor(s, 4, 64);
            s += __shfl_xor(s, 8, 64);
            rs[r] = s;
        }
        if (lm == 0) {          // 4 lanes x 16B consecutive = full 64B line
            const int rr = wr * 32 + fr * 16 + lq * 4;
            if (TWO_STAGE) *(f32x4*)(dstr + wc * 64 + rr) = rs;
            else {
                #pragma unroll
                for (int r = 0; r < 4; ++r)
                    atomicAdd(&S[ri * AT + rr + r], rs[r]);
            }
        }
    }
}

// ---------------------------------------------------------------------------
// Kernel 3 (R12 NEW): FUSED gather + loss. Replaces reduce_kernel (16-chunk
// S2 pass) + loss2_kernel: one launch instead of two, no S2 round-trip.
// Grid 256 blocks x 256 threads: block b owns rows i = b*32..b*32+31 and
// partners i+8192. Thread (j = tid&31, k = tid>>5): 8 threads stride row
// (i|p)'s partial list (addressing verbatim from the R10-verified
// reduce_kernel); LDS 8-way fold; lanes 0..31 of wave 0 compute
// v = 0.5(log den1 + log den2) - 2*pos, wave-reduce, one atomicAdd/block.
// Within a block all 32 rows share strip ri and col tile tj (32 consecutive
// rows inside a 64-strip / 128-tile) -> uniform T, coalesced 128B runs.
// out zeroed by normalize (stream-ordered).
// ---------------------------------------------------------------------------
__global__ __launch_bounds__(256) void reduce_loss_kernel(
    const float* __restrict__ part, const float* __restrict__ pos,
    float* __restrict__ out)
{
    const int tid = threadIdx.x;
    const int j = tid & 31;              // row within block
    const int k = tid >> 5;              // stride lane 0..7
    const int i = blockIdx.x * 32 + j;   // row in [0, 8192)

    __shared__ float red1[256], red2[256];

    float den[2];
    #pragma unroll
    for (int h = 0; h < 2; ++h) {
        const int r = i + h * N_ROWS;    // Z row
        const int ri = r >> 6, rr = r & 63;
        const int gg = ri >> 3;
        const int nseg = 32 - gg;
        const int sid0 = 260 * gg - 4 * gg * gg + (ri & 7) * nseg;
        const int tj = r >> 7, cc = r & 127;
        const int nr = 2 * tj + 2;       // strips covering col tile tj
        const int T = 2 * nseg + 2 * nr;

        float s = 0.0f;
        for (int m = k; m < T; m += 8) {
            size_t addr;
            if (m < 2 * nseg) {
                addr = (size_t)(sid0 + (m >> 1)) * PSTRIDE + (m & 1) * 64 + rr;
            } else {
                const int m2 = m - 2 * nseg;
                const int rip = m2 >> 1;            // source strip
                const int dtj = tj - (rip >> 1);
                const int gp = rip >> 3;
                const int sidc = 260 * gp - 4 * gp * gp + (rip & 7) * (32 - gp)
                               + (dtj >> 2);
                addr = (size_t)sidc * PSTRIDE + 128 + (dtj & 3) * 256
                     + (m2 & 1) * 128 + cc;
            }
            s += part[addr];
        }
        den[h] = s;
    }
    red1[j * 8 + k] = den[0];
    red2[j * 8 + k] = den[1];
    __syncthreads();

    if (tid < 32) {
        float d1 = 0.0f, d2 = 0.0f;
        #pragma unroll
        for (int kk = 0; kk < 8; ++kk) {
            d1 += red1[tid * 8 + kk];
            d2 += red2[tid * 8 + kk];
        }
        float vv = 0.5f * (logf(d1) + logf(d2))
                 - TAU_INV * pos[blockIdx.x * 32 + tid];
        vv += __shfl_xor(vv, 1, 64);
        vv += __shfl_xor(vv, 2, 64);
        vv += __shfl_xor(vv, 4, 64);
        vv += __shfl_xor(vv, 8, 64);
        vv += __shfl_xor(vv, 16, 64);
        if (tid == 0) atomicAdd(out, vv * (1.0f / N_ROWS));
    }
}

// Fallback loss (atomic path, only if ws too small — never expected).
__global__ __launch_bounds__(256) void loss_kernel(
    const float* __restrict__ S, const float* __restrict__ pos,
    float* __restrict__ out)
{
    const int i = blockIdx.x * 256 + threadIdx.x;
    float v = 0.5f * (logf(S[i]) + logf(S[N_ROWS + i])) - TAU_INV * pos[i];

    __shared__ float red[4];
    #pragma unroll
    for (int m = 1; m < 64; m <<= 1) v += __shfl_xor(v, m, 64);
    if ((threadIdx.x & 63) == 0) red[threadIdx.x >> 6] = v;
    __syncthreads();
    if (threadIdx.x == 0)
        atomicAdd(out, (red[0] + red[1] + red[2] + red[3]) * (1.0f / N_ROWS));
}

// ---------------------------------------------------------------------------
extern "C" void kernel_launch(void* const* d_in, const int* in_sizes, int n_in,
                              void* d_out, int out_size, void* d_ws, size_t ws_size,
                              hipStream_t stream)
{
    const float* z1 = (const float*)d_in[0];
    const float* z2 = (const float*)d_in[1];
    float* out = (float*)d_out;

    char* ws = (char*)d_ws;
    unsigned char* Z8 = (unsigned char*)ws;              // 16384*256 = 4 MB
    float* pos  = (float*)(ws + 4194304);                // 32 KB
    float* S    = (float*)(ws + 4227072);                // NZ floats (fallback)
    float* part = (float*)(ws + 5275648);                // 4224*1152*4 = 19.5 MB
    const size_t need = 5275648 + (size_t)NSEG * PSTRIDE * 4;

    normalize_kernel<<<N_ROWS / 4, 256, 0, stream>>>(z1, z2, Z8, pos, out);

    if (ws_size >= need) {
        gram_kernel<true><<<NSEG, 256, 0, stream>>>(Z8, part, nullptr);
        reduce_loss_kernel<<<N_ROWS / 32, 256, 0, stream>>>(part, pos, out);
    } else {
        hipMemsetAsync(S, 0, NZ * sizeof(float), stream);
        hipMemsetAsync(out, 0, sizeof(float), stream);
        gram_kernel<false><<<NSEG, 256, 0, stream>>>(Z8, nullptr, S);
        loss_kernel<<<N_ROWS / 256, 256, 0, stream>>>(S, pos, out);
    }
}

// Round 13
// 141.516 us; speedup vs baseline: 2.2476x; 1.1583x over previous
//
#include <hip/hip_runtime.h>
#include <hip/hip_bf16.h>
#include <hip/hip_fp8.h>

#define N_ROWS 8192
#define NZ 16384           // rows of Z = [An; Bn]
#define DIM 256
#define TAU_INV 2.0f
#define BT 128             // col tile width
#define AT 64              // row tile height (A strip)
#define NTILE 128          // NZ / BT  (col tiles)
#define SEGT 4             // col tiles per segment
#define NSEG 4224          // sum over ri of ceil((128 - (ri>>1))/4)
#define PSTRIDE 1152       // floats/segment: 2*64 row-partials + 4*2*128 col-partials

typedef float f32x4 __attribute__((ext_vector_type(4)));
typedef long lx2 __attribute__((ext_vector_type(2)));   // 16B = 2 fp8 MFMA operands

// ---------------------------------------------------------------------------
// Kernel 1: one WAVE per row. L2-normalize, scale by 16, quantize to OCP fp8
// e4m3, write Z8 K-INTERLEAVED: each 64B chunk stores its eight 8B K-groups
// as [g0 g4 g1 g5 g2 g6 g3 g7] so one 16B granule = operand pair (g, g+4)
// for two consecutive MFMA K-steps. pos[i] = (1/256)*dot(quantized an, bn).
// Also zeroes out[0] (stream-ordered before the fused reduce+loss).
// ---------------------------------------------------------------------------
__global__ __launch_bounds__(256) void normalize_kernel(
    const float* __restrict__ z1, const float* __restrict__ z2,
    unsigned char* __restrict__ Z8, float* __restrict__ pos,
    float* __restrict__ out)
{
    const int tid = threadIdx.x;
    const int wave = tid >> 6;
    const int lane = tid & 63;
    const int row = blockIdx.x * 4 + wave;      // 0..8191

    if (blockIdx.x == 0 && tid == 0) out[0] = 0.0f;

    const float4 a = ((const float4*)(z1 + (size_t)row * DIM))[lane];
    const float4 b = ((const float4*)(z2 + (size_t)row * DIM))[lane];

    auto wsum = [&](float v) -> float {
        #pragma unroll
        for (int m = 1; m < 64; m <<= 1) v += __shfl_xor(v, m, 64);
        return v;
    };

    const float na2 = wsum(a.x*a.x + a.y*a.y + a.z*a.z + a.w*a.w);
    const float nb2 = wsum(b.x*b.x + b.y*b.y + b.z*b.z + b.w*b.w);
    const float sa = 16.0f / sqrtf(na2);   // norms ~16; eps never binds
    const float sb = 16.0f / sqrtf(nb2);

    const float av[4] = {a.x*sa, a.y*sa, a.z*sa, a.w*sa};
    const float bv[4] = {b.x*sb, b.y*sb, b.z*sb, b.w*sb};
    unsigned char pa[4], pb[4];
    float qd = 0.0f;
    #pragma unroll
    for (int k = 0; k < 4; ++k) {
        __hip_fp8_e4m3 qa(av[k]);
        __hip_fp8_e4m3 qb(bv[k]);
        pa[k] = qa.__x; pb[k] = qb.__x;
        qd += float(qa) * float(qb);
    }
    const int g  = (lane >> 1) & 7;
    const int pp = ((g & 3) << 1) | (g >> 2);          // interleaved 8B slot
    const int off = (lane >> 4) * 64 + pp * 8 + (lane & 1) * 4;
    *(uchar4*)(Z8 + (size_t)row * DIM + off) = *(uchar4*)pa;
    *(uchar4*)(Z8 + (size_t)(N_ROWS + row) * DIM + off) = *(uchar4*)pb;

    qd = wsum(qd);
    if (lane == 0) pos[row] = qd * 0.00390625f;   // /256 -> quantized sim
}

// ---------------------------------------------------------------------------
// Kernel 2 (VERBATIM R10 — measured best: gram 72.5us, VGPR 64, 0 conflicts):
// symmetric fp8 gram, 64x128 tiles, strip-segmented SEGT=4, 2-slot
// __syncthreads prefetch ring, A in registers, raw v_exp_f32.
// R11 lesson (m68/m69 quanta): HW wave slots step at VGPR<=64 (8/SIMD) and
// <=128 (4/SIMD) with NO intermediate; this kernel's wave cannot fit the
// 64-quantum with more per-wave state -> 16 waves/CU is the occupancy
// ceiling. Schedule restructuring proven null (R6/R7). Structure final.
// ---------------------------------------------------------------------------
template <bool TWO_STAGE>
__global__ __launch_bounds__(256, 4) void gram_kernel(
    const unsigned char* __restrict__ Z,
    float* __restrict__ part, float* __restrict__ S)
{
    // XCD band remap over segments (4224 = 8 * 528), then segment decode.
    const int sid = (blockIdx.x & 7) * (NSEG / 8) + (blockIdx.x >> 3);
    // group g: strips ri = 8g..8g+7 each have v = 32-g segments;
    // cum(g) = 260g - 4g^2 segments before group g.
    int g = (int)((260.0f - sqrtf(67600.0f - 16.0f * (float)sid)) * 0.125f);
    g = g < 0 ? 0 : (g > 31 ? 31 : g);
    while (260 * g - 4 * g * g > sid) --g;
    while (g < 31 && 260 * (g + 1) - 4 * (g + 1) * (g + 1) <= sid) ++g;
    const int local = sid - (260 * g - 4 * g * g);
    const int v  = 32 - g;                 // segments per strip in this group
    const int r8i = local / v;
    const int s4 = local - r8i * v;
    const int ri = 8 * g + r8i;            // row strip 0..255
    const int tj0 = (ri >> 1) + SEGT * s4; // first col tile
    const int nt = (NTILE - tj0 < SEGT) ? (NTILE - tj0) : SEGT;

    __shared__ unsigned char Ls[32768];   // B ring slots 0/1 (16KB each)

    const int tid  = threadIdx.x;
    const int wave = tid >> 6;
    const int lane = tid & 63;
    const int wr = wave >> 1, wc = wave & 1;   // wave grid 2x2 over 64x128
    const int lm = lane & 15, lq = lane >> 4;

    // ---- A fragments: global -> regs once per segment (R5/R7-proven layout)
    lx2 aR[2][2][2];                       // [kh][set][fr]
    {
        const unsigned char* pa =
            Z + (size_t)(ri * AT + wr * 32 + lm) * DIM + lq * 16;
        #pragma unroll
        for (int fr = 0; fr < 2; ++fr)
            #pragma unroll
            for (int kh = 0; kh < 2; ++kh)
                #pragma unroll
                for (int s = 0; s < 2; ++s)
                    aR[kh][s][fr] =
                        *(const lx2*)(pa + fr * 4096 + kh * 128 + s * 64);
    }

    // ---- staging lane geometry (width-16: 1KB instr = 8 rows x 8 granules)
    const int r8 = lane >> 3;                   // row within 8-row group
    const int pg = lane & 7;                    // LDS granule slot
    const int G0 = pg ^ (r8 >> 1);              // global granule, even instrs
    const int dlt = 64 - ((G0 & 4) << 5);       // odd instrs: granule G0^4
    const unsigned char* pB0 =
        Z + (size_t)(tj0 * BT + wave * 32 + r8) * DIM + (G0 << 4);

    auto stageB = [&](const unsigned char* pb, int kh, int sl) {
        #pragma unroll
        for (int c = 0; c < 4; ++c) {           // rows wave*32 + c*8 + r8
            const unsigned char* gb = ((c & 1) ? pb + dlt : pb) + c * 2048 + kh * 128;
            __builtin_amdgcn_global_load_lds(
                (const __attribute__((address_space(1))) void*)gb,
                (__attribute__((address_space(3))) void*)
                    (Ls + sl * 16384 + (wave * 4 + c) * 1024), 16, 0, 0);
        }
    };

    stageB(pB0, 0, 0);   // prologue: B(tile0, kh0) -> slot0

    // ---- B frag-read bases (invariant across the segment; R4 swizzle)
    const int s0 = (lq ^ (lm >> 1)) << 4;       // slot of granule lq
    const int s1 = s0 ^ 64;                     // slot of granule lq^4
    const unsigned char* LB = Ls + (wc * 64 + lm) * 128;   // + slot*16K

    const float SC = 2.8853900817779268f / 256.0f;   // exp(2*sim), dot=256*sim

    f32x4 rowacc[2] = {};   // per-lane row partial, accumulated over segment

    for (int t = 0; t < nt; ++t) {
        f32x4 acc[2][4] = {};
        #pragma unroll
        for (int kh = 0; kh < 2; ++kh) {
            __syncthreads();    // drains stage(h) [one compute phase of cover]
            if (kh == 0)            stageB(pB0 + (size_t)t * 32768, 1, 1);
            else if (t + 1 < nt)    stageB(pB0 + (size_t)(t + 1) * 32768, 0, 0);

            const unsigned char* lb = LB + (kh << 14);   // slot == kh
            lx2 bP[4];
            __builtin_amdgcn_s_setprio(1);
            #pragma unroll
            for (int f = 0; f < 4; ++f) bP[f] = *(const lx2*)(lb + s0 + f * 2048);
            #pragma unroll
            for (int fr = 0; fr < 2; ++fr)
                #pragma unroll
                for (int fc = 0; fc < 4; ++fc) {
                    acc[fr][fc] = __builtin_amdgcn_mfma_f32_16x16x32_fp8_fp8(
                        aR[kh][0][fr].x, bP[fc].x, acc[fr][fc], 0, 0, 0);
                    acc[fr][fc] = __builtin_amdgcn_mfma_f32_16x16x32_fp8_fp8(
                        aR[kh][0][fr].y, bP[fc].y, acc[fr][fc], 0, 0, 0);
                }
            #pragma unroll
            for (int f = 0; f < 4; ++f) bP[f] = *(const lx2*)(lb + s1 + f * 2048);
            #pragma unroll
            for (int fr = 0; fr < 2; ++fr)
                #pragma unroll
                for (int fc = 0; fc < 4; ++fc) {
                    acc[fr][fc] = __builtin_amdgcn_mfma_f32_16x16x32_fp8_fp8(
                        aR[kh][1][fr].x, bP[fc].x, acc[fr][fc], 0, 0, 0);
                    acc[fr][fc] = __builtin_amdgcn_mfma_f32_16x16x32_fp8_fp8(
                        aR[kh][1][fr].y, bP[fc].y, acc[fr][fc], 0, 0, 0);
                }
            __builtin_amdgcn_s_setprio(0);
        }

        // ---- per-tile epilogue (LDS-free; overlaps in-flight stage)
        // raw v_exp_f32: args bounded to +-2.89, fixup-free (R10-proven)
        #pragma unroll
        for (int fr = 0; fr < 2; ++fr)
            #pragma unroll
            for (int fc = 0; fc < 4; ++fc)
                #pragma unroll
                for (int r = 0; r < 4; ++r)
                    acc[fr][fc][r] = __builtin_amdgcn_exp2f(acc[fr][fc][r] * SC);

        const int tj = tj0 + t;
        if (tj == (ri >> 1)) {   // only tile of the segment crossing diagonal
            const int add = (ri & 1) << 6;    // odd strip: rows sit 64 below
            #pragma unroll
            for (int fr = 0; fr < 2; ++fr) {
                const int ciloc = wr * 32 + fr * 16 + lq * 4;
                #pragma unroll
                for (int fc = 0; fc < 4; ++fc) {
                    const int cj = wc * 64 + fc * 16 + lm;
                    #pragma unroll
                    for (int r = 0; r < 4; ++r)
                        if (cj <= ciloc + r + add) acc[fr][fc][r] = 0.0f;
                }
            }
        }

        // row partials: accumulate in registers across the segment
        #pragma unroll
        for (int fr = 0; fr < 2; ++fr)
            #pragma unroll
            for (int r = 0; r < 4; ++r)
                rowacc[fr][r] += acc[fr][0][r] + acc[fr][1][r]
                               + acc[fr][2][r] + acc[fr][3][r];

        // col partials per tile (B changes each tile); stores drained by sync
        float* dstc = TWO_STAGE ? (part + (size_t)sid * PSTRIDE + 128 + t * 256)
                                : nullptr;
        #pragma unroll
        for (int fc = 0; fc < 4; ++fc) {
            float s = 0.0f;
            #pragma unroll
            for (int fr = 0; fr < 2; ++fr)
                #pragma unroll
                for (int r = 0; r < 4; ++r) s += acc[fr][fc][r];
            s += __shfl_xor(s, 16, 64);
            s += __shfl_xor(s, 32, 64);
            if (lq == 0) {      // 16 lanes x 4B consecutive = full 64B line
                const int cc = wc * 64 + fc * 16 + lm;
                if (TWO_STAGE) dstc[wr * 128 + cc] = s;
                else atomicAdd(&S[tj * BT + cc], s);
            }
        }
    }

    // ---- segment epilogue: lane-reduce + store row partials ONCE
    float* dstr = TWO_STAGE ? (part + (size_t)sid * PSTRIDE) : nullptr;
    #pragma unroll
    for (int fr = 0; fr < 2; ++fr) {
        f32x4 rs;
        #pragma unroll
        for (int r = 0; r < 4; ++r) {
            float s = rowacc[fr][r];
            s += __shfl_xor(s, 1, 64);
            s += __shfl_xor(s, 2, 64);
            s += __shfl_xor(s, 4, 64);
            s += __shfl_xor(s, 8, 64);
            rs[r] = s;
        }
        if (lm == 0) {          // 4 lanes x 16B consecutive = full 64B line
            const int rr = wr * 32 + fr * 16 + lq * 4;
            if (TWO_STAGE) *(f32x4*)(dstr + wc * 64 + rr) = rs;
            else {
                #pragma unroll
                for (int r = 0; r < 4; ++r)
                    atomicAdd(&S[ri * AT + rr + r], rs[r]);
            }
        }
    }
}

// ---------------------------------------------------------------------------
// Kernel 3 (R13 = R12 fused kernel, parallelism fixed): FUSED gather + loss.
// R12 lesson: 256 blocks x 256 threads = 1 block/CU x 4 waves for a
// latency-bound scatter with 4.5x per-block imbalance -> +18us. Fix: 1024
// threads (16 waves/CU), 32-way m-stride -> worst block ~18 independent
// loads/lane, fully MLP-overlapped. Addressing verbatim from the
// R10-verified reduce_kernel. LDS fold padded stride-33 (conflict-free).
// out zeroed by normalize (stream-ordered).
// ---------------------------------------------------------------------------
__global__ __launch_bounds__(1024) void reduce_loss_kernel(
    const float* __restrict__ part, const float* __restrict__ pos,
    float* __restrict__ out)
{
    const int tid = threadIdx.x;
    const int j = tid & 31;              // row within block
    const int k = tid >> 5;              // stride lane 0..31
    const int i = blockIdx.x * 32 + j;   // row in [0, 8192)

    __shared__ float red1[32 * 33], red2[32 * 33];

    float den[2];
    #pragma unroll
    for (int h = 0; h < 2; ++h) {
        const int r = i + h * N_ROWS;    // Z row
        const int ri = r >> 6, rr = r & 63;
        const int gg = ri >> 3;
        const int nseg = 32 - gg;
        const int sid0 = 260 * gg - 4 * gg * gg + (ri & 7) * nseg;
        const int tj = r >> 7, cc = r & 127;
        const int nr = 2 * tj + 2;       // strips covering col tile tj
        const int T = 2 * nseg + 2 * nr;

        float s = 0.0f;
        for (int m = k; m < T; m += 32) {
            size_t addr;
            if (m < 2 * nseg) {
                addr = (size_t)(sid0 + (m >> 1)) * PSTRIDE + (m & 1) * 64 + rr;
            } else {
                const int m2 = m - 2 * nseg;
                const int rip = m2 >> 1;            // source strip
                const int dtj = tj - (rip >> 1);
                const int gp = rip >> 3;
                const int sidc = 260 * gp - 4 * gp * gp + (rip & 7) * (32 - gp)
                               + (dtj >> 2);
                addr = (size_t)sidc * PSTRIDE + 128 + (dtj & 3) * 256
                     + (m2 & 1) * 128 + cc;
            }
            s += part[addr];
        }
        den[h] = s;
    }
    red1[j * 33 + k] = den[0];
    red2[j * 33 + k] = den[1];
    __syncthreads();

    if (tid < 32) {
        float d1 = 0.0f, d2 = 0.0f;
        #pragma unroll
        for (int kk = 0; kk < 32; ++kk) {
            d1 += red1[tid * 33 + kk];
            d2 += red2[tid * 33 + kk];
        }
        float vv = 0.5f * (logf(d1) + logf(d2))
                 - TAU_INV * pos[blockIdx.x * 32 + tid];
        vv += __shfl_xor(vv, 1, 64);
        vv += __shfl_xor(vv, 2, 64);
        vv += __shfl_xor(vv, 4, 64);
        vv += __shfl_xor(vv, 8, 64);
        vv += __shfl_xor(vv, 16, 64);
        if (tid == 0) atomicAdd(out, vv * (1.0f / N_ROWS));
    }
}

// Fallback loss (atomic path, only if ws too small — never expected).
__global__ __launch_bounds__(256) void loss_kernel(
    const float* __restrict__ S, const float* __restrict__ pos,
    float* __restrict__ out)
{
    const int i = blockIdx.x * 256 + threadIdx.x;
    float v = 0.5f * (logf(S[i]) + logf(S[N_ROWS + i])) - TAU_INV * pos[i];

    __shared__ float red[4];
    #pragma unroll
    for (int m = 1; m < 64; m <<= 1) v += __shfl_xor(v, m, 64);
    if ((threadIdx.x & 63) == 0) red[threadIdx.x >> 6] = v;
    __syncthreads();
    if (threadIdx.x == 0)
        atomicAdd(out, (red[0] + red[1] + red[2] + red[3]) * (1.0f / N_ROWS));
}

// ---------------------------------------------------------------------------
extern "C" void kernel_launch(void* const* d_in, const int* in_sizes, int n_in,
                              void* d_out, int out_size, void* d_ws, size_t ws_size,
                              hipStream_t stream)
{
    const float* z1 = (const float*)d_in[0];
    const float* z2 = (const float*)d_in[1];
    float* out = (float*)d_out;

    char* ws = (char*)d_ws;
    unsigned char* Z8 = (unsigned char*)ws;              // 16384*256 = 4 MB
    float* pos  = (float*)(ws + 4194304);                // 32 KB
    float* S    = (float*)(ws + 4227072);                // NZ floats (fallback)
    float* part = (float*)(ws + 5275648);                // 4224*1152*4 = 19.5 MB
    const size_t need = 5275648 + (size_t)NSEG * PSTRIDE * 4;

    normalize_kernel<<<N_ROWS / 4, 256, 0, stream>>>(z1, z2, Z8, pos, out);

    if (ws_size >= need) {
        gram_kernel<true><<<NSEG, 256, 0, stream>>>(Z8, part, nullptr);
        reduce_loss_kernel<<<N_ROWS / 32, 1024, 0, stream>>>(part, pos, out);
    } else {
        hipMemsetAsync(S, 0, NZ * sizeof(float), stream);
        hipMemsetAsync(out, 0, sizeof(float), stream);
        gram_kernel<false><<<NSEG, 256, 0, stream>>>(Z8, nullptr, S);
        loss_kernel<<<N_ROWS / 256, 256, 0, stream>>>(S, pos, out);
    }
}